// Round 2
// baseline (48350.418 us; speedup 1.0000x reference)
//
#include <hip/hip_runtime.h>

#define HIDN 150
#define NG   600     // 4*HIDN gates
#define NGP  640     // padded gate width (zero-padded in repacked weights)
#define TT   512
#define NBATCH 256

// ---------------- weight repack / bias prep ----------------
// Wtg: [K][640]   Wtg[k][n] = Wih[n][k]  (0 for n>=600)
// Wts: [150][640] Wts[k][n] = Whh[n][k]  (0 for n>=600)
// bsum[g] = bih[g]+bhh[g]
__global__ __launch_bounds__(256) void prep_kernel(
    const float* __restrict__ Wih, const float* __restrict__ Whh,
    const float* __restrict__ bih, const float* __restrict__ bhh,
    int K, float* __restrict__ Wtg, float* __restrict__ Wts,
    float* __restrict__ bsum)
{
    int i = blockIdx.x * 256 + threadIdx.x;
    int ngemm = K * NGP;
    if (i < ngemm) {
        int k = i / NGP, n = i % NGP;
        Wtg[i] = (n < NG) ? Wih[(size_t)n * K + k] : 0.f;
    } else if (i < ngemm + HIDN * NGP) {
        int j = i - ngemm;
        int k = j / NGP, n = j % NGP;
        Wts[j] = (n < NG) ? Whh[(size_t)n * HIDN + k] : 0.f;
    } else if (i < ngemm + HIDN * NGP + NGP) {
        int g = i - ngemm - HIDN * NGP;
        bsum[g] = (g < NG) ? (bih[g] + bhh[g]) : 0.f;
    }
}

// ---------------- x_proj GEMM ----------------
// Chunked: M rows = NBc*Tc laid out [bb][tloc]; row rg -> bb=rg>>lTc, tloc=rg&(Tc-1).
// A (H buffer) is [NBc][512][150]; C (G chunk) is [NBc*Tc][600] chunk-linear.
#define MT 128
#define NT 128
#define KT 32

__global__ __launch_bounds__(256) void gemm_kernel(
    const float* __restrict__ A,       // H buffer [NBc][512][150] (layers 1-3) or nullptr
    const int*   __restrict__ gather,  // x indices (layer 0) or nullptr
    const float* __restrict__ emb,     // [50000][300]
    int K,
    const float* __restrict__ Bt,      // [K][640] repacked W^T
    const float* __restrict__ bsum,    // [640]
    const int*   __restrict__ lengths,
    float* __restrict__ C,             // [NBc*Tc][600]
    int b_off, int t0, int lTc)
{
    int Tcm1 = (1 << lTc) - 1;
    int m0 = blockIdx.x * MT;
    int n0 = blockIdx.y * NT;
    if (lTc >= 7) {                    // tile lies within a single batch: early skip
        int b = b_off + (m0 >> lTc);
        int tmax = max(lengths[b], lengths[b ^ 1]);   // scan pairs (2i,2i+1)
        if (t0 + (m0 & Tcm1) >= tmax) return;         // rows never read downstream
    }

    __shared__ __align__(16) float As[MT][36];    // stride 36: f4-aligned, breaks ty conflicts
    __shared__ __align__(16) float Bs[KT][NT];

    int tid = threadIdx.x;
    int tx = tid & 15, ty = tid >> 4;

    float acc[8][8];
    #pragma unroll
    for (int i = 0; i < 8; ++i)
        #pragma unroll
        for (int j = 0; j < 8; ++j) acc[i][j] = 0.f;

    for (int k0 = 0; k0 < K; k0 += KT) {
        #pragma unroll
        for (int it = 0; it < 16; ++it) {
            int idx = it * 256 + tid;
            int c = idx & (KT - 1), r = idx >> 5;
            int kk = k0 + c;
            float v = 0.f;
            if (kk < K) {
                int rg = m0 + r;
                int bb = rg >> lTc, tl = rg & Tcm1;
                const float* row = gather
                    ? (emb + (size_t)gather[(b_off + bb) * TT + t0 + tl] * 300)
                    : (A + ((size_t)bb * TT + t0 + tl) * HIDN);
                v = row[kk];
            }
            As[r][c] = v;
        }
        #pragma unroll
        for (int it = 0; it < 16; ++it) {
            int idx = it * 256 + tid;
            int n = idx & (NT - 1), kk = idx >> 7;
            Bs[kk][n] = (k0 + kk < K) ? Bt[(size_t)(k0 + kk) * NGP + n0 + n] : 0.f;
        }
        __syncthreads();
        #pragma unroll
        for (int k4 = 0; k4 < KT / 4; ++k4) {
            float a4[8][4];
            #pragma unroll
            for (int i = 0; i < 8; ++i) {
                float4 t4 = *(const float4*)&As[ty + 16 * i][k4 * 4];
                a4[i][0] = t4.x; a4[i][1] = t4.y; a4[i][2] = t4.z; a4[i][3] = t4.w;
            }
            #pragma unroll
            for (int kk = 0; kk < 4; ++kk) {
                float4 bA = *(const float4*)&Bs[k4 * 4 + kk][tx * 8];
                float4 bB = *(const float4*)&Bs[k4 * 4 + kk][tx * 8 + 4];
                float bv[8] = {bA.x, bA.y, bA.z, bA.w, bB.x, bB.y, bB.z, bB.w};
                #pragma unroll
                for (int i = 0; i < 8; ++i) {
                    float a = a4[i][kk];
                    #pragma unroll
                    for (int j = 0; j < 8; ++j) acc[i][j] += a * bv[j];
                }
            }
        }
        __syncthreads();
    }

    int n = n0 + tx * 8;
    float4 bs1 = *(const float4*)&bsum[n];
    float4 bs2 = *(const float4*)&bsum[n + 4];
    #pragma unroll
    for (int i = 0; i < 8; ++i) {
        float* crow = C + (size_t)(m0 + ty + 16 * i) * NG;
        if (n < NG) {
            float4 v = make_float4(acc[i][0] + bs1.x, acc[i][1] + bs1.y,
                                   acc[i][2] + bs1.z, acc[i][3] + bs1.w);
            *(float4*)&crow[n] = v;
        }
        if (n + 4 < NG) {
            float4 v = make_float4(acc[i][4] + bs2.x, acc[i][5] + bs2.y,
                                   acc[i][6] + bs2.z, acc[i][7] + bs2.w);
            *(float4*)&crow[n + 4] = v;
        }
    }
}

// ---------------- recurrent scan (one block per batch-pair, t-chunked) ----------------
__global__ __launch_bounds__(256) void scan_kernel(
    const float* __restrict__ G,       // [NBc][Tc][600] chunk of x_proj+bias
    const float* __restrict__ Wt,      // [150][640] Whh^T padded
    const int*   __restrict__ lengths,
    float* __restrict__ H,             // [NBc][512][150] in-place layer output
    float* __restrict__ hnb,           // [256][150] last-h capture (global batch idx)
    float* __restrict__ hst,           // [NBc][150] h carry
    float* __restrict__ cst,           // [NBc][150] c carry
    int b_off, int t0, int Tc)
{
    __shared__ __align__(8) float h_s[HIDN][2];
    __shared__ float gate_s[2][NG];

    int tid = threadIdx.x;
    int l0 = blockIdx.x * 2, l1 = l0 + 1;     // chunk-local batch ids
    int b0 = b_off + l0, b1 = b_off + l1;     // global batch ids
    int len0 = lengths[b0], len1 = lengths[b1];
    int tmax = min(max(len0, len1), t0 + Tc);

    float c0 = 0.f, c1 = 0.f;
    if (tid < HIDN) {
        if (t0 == 0) { h_s[tid][0] = 0.f; h_s[tid][1] = 0.f; }
        else {
            h_s[tid][0] = hst[l0 * HIDN + tid];
            h_s[tid][1] = hst[l1 * HIDN + tid];
            c0 = cst[l0 * HIDN + tid];
            c1 = cst[l1 * HIDN + tid];
        }
    }
    __syncthreads();

    int j0 = tid, j1 = tid + 256, j2 = tid + 512;
    bool lane2 = (tid < 128);          // j2 < 640 (padded weight width); wave-uniform

    for (int t = t0; t < tmax; ++t) {
        const float* g0p = G + ((size_t)l0 * Tc + (t - t0)) * NG;
        const float* g1p = G + ((size_t)l1 * Tc + (t - t0)) * NG;
        float a00 = g0p[j0], a01 = g1p[j0];
        float a10 = g0p[j1], a11 = g1p[j1];
        float a20 = 0.f, a21 = 0.f;
        if (j2 < NG) { a20 = g0p[j2]; a21 = g1p[j2]; }
        #pragma unroll 10
        for (int k = 0; k < HIDN; ++k) {
            float2 h2 = *(const float2*)&h_s[k][0];   // LDS broadcast
            const float* wr = Wt + k * NGP;
            float w0 = wr[j0];
            float w1 = wr[j1];
            a00 += w0 * h2.x; a01 += w0 * h2.y;
            a10 += w1 * h2.x; a11 += w1 * h2.y;
            if (lane2) {
                float w2 = wr[j2];
                a20 += w2 * h2.x; a21 += w2 * h2.y;
            }
        }
        gate_s[0][j0] = a00; gate_s[1][j0] = a01;
        gate_s[0][j1] = a10; gate_s[1][j1] = a11;
        if (j2 < NG) { gate_s[0][j2] = a20; gate_s[1][j2] = a21; }
        __syncthreads();
        if (tid < HIDN) {
            int u = tid;
            {   // batch 0
                float ig = gate_s[0][u], fg = gate_s[0][u + HIDN];
                float gg = gate_s[0][u + 2 * HIDN], og = gate_s[0][u + 3 * HIDN];
                float iv = 1.f / (1.f + __expf(-ig));
                float fv = 1.f / (1.f + __expf(-fg));
                float gv = tanhf(gg);
                float ov = 1.f / (1.f + __expf(-og));
                float cn = fv * c0 + iv * gv;
                float hv = ov * tanhf(cn);
                bool upd = (t < len0);
                if (upd) { c0 = cn; h_s[u][0] = hv; }
                H[((size_t)l0 * TT + t) * HIDN + u] = upd ? hv : 0.f;
                if (t == len0 - 1) hnb[b0 * HIDN + u] = hv;
            }
            {   // batch 1
                float ig = gate_s[1][u], fg = gate_s[1][u + HIDN];
                float gg = gate_s[1][u + 2 * HIDN], og = gate_s[1][u + 3 * HIDN];
                float iv = 1.f / (1.f + __expf(-ig));
                float fv = 1.f / (1.f + __expf(-fg));
                float gv = tanhf(gg);
                float ov = 1.f / (1.f + __expf(-og));
                float cn = fv * c1 + iv * gv;
                float hv = ov * tanhf(cn);
                bool upd = (t < len1);
                if (upd) { c1 = cn; h_s[u][1] = hv; }
                H[((size_t)l1 * TT + t) * HIDN + u] = upd ? hv : 0.f;
                if (t == len1 - 1) hnb[b1 * HIDN + u] = hv;
            }
        }
        __syncthreads();
    }

    if (tid < HIDN) {
        hst[l0 * HIDN + tid] = h_s[tid][0];
        hst[l1 * HIDN + tid] = h_s[tid][1];
        cst[l0 * HIDN + tid] = c0;
        cst[l1 * HIDN + tid] = c1;
    }
}

// ---------------- fc1+relu+fc2 head ----------------
__global__ __launch_bounds__(256) void head_kernel(
    const float* __restrict__ hnb, const float* __restrict__ fc1_w,
    const float* __restrict__ fc1_b, const float* __restrict__ fc2_w,
    const float* __restrict__ fc2_b, float* __restrict__ out)
{
    __shared__ float hs[HIDN];
    __shared__ float zs[HIDN];
    int b = blockIdx.x, tid = threadIdx.x;
    if (tid < HIDN) hs[tid] = hnb[b * HIDN + tid];
    __syncthreads();
    if (tid < HIDN) {
        float acc = fc1_b[tid];
        const float* wr = fc1_w + (size_t)tid * HIDN;
        #pragma unroll 5
        for (int k = 0; k < HIDN; ++k) acc += wr[k] * hs[k];
        zs[tid] = fmaxf(acc, 0.f);
    }
    __syncthreads();
    if (tid == 0) {
        float s = fc2_b[0];
        for (int k = 0; k < HIDN; ++k) s += fc2_w[k] * zs[k];
        out[b] = s;
    }
}

extern "C" void kernel_launch(void* const* d_in, const int* in_sizes, int n_in,
                              void* d_out, int out_size, void* d_ws, size_t ws_size,
                              hipStream_t stream)
{
    const int*   x       = (const int*)d_in[0];
    const int*   lengths = (const int*)d_in[1];
    const float* emb     = (const float*)d_in[2];
    const float *Wih[4], *Whh[4], *bih[4], *bhh[4];
    for (int l = 0; l < 4; ++l) {
        Wih[l] = (const float*)d_in[3 + 4 * l];
        Whh[l] = (const float*)d_in[4 + 4 * l];
        bih[l] = (const float*)d_in[5 + 4 * l];
        bhh[l] = (const float*)d_in[6 + 4 * l];
    }
    const float* fc1_w = (const float*)d_in[19];
    const float* fc1_b = (const float*)d_in[20];
    const float* fc2_w = (const float*)d_in[21];
    const float* fc2_b = (const float*)d_in[22];

    // ---- adaptive workspace sizing (ws_size is constant across calls -> graph-safe) ----
    size_t wf = ws_size / sizeof(float);
    const size_t WFIX = 768000 + 384000 + 2560 + 38400;   // Wtg + Wts + bsm + hnb
    int NBc = 0, Tc = 0;
    for (int nb = 256; nb >= 16; nb >>= 1) {
        for (int tc = 512; tc >= 8; tc >>= 1) {
            size_t need = WFIX + (size_t)nb * 2 * HIDN          // h/c carry
                        + (size_t)nb * TT * HIDN                 // H (single, in-place)
                        + (size_t)nb * tc * NG;                  // G chunk
            if (need <= wf) { NBc = nb; Tc = tc; break; }
        }
        if (NBc) break;
    }
    if (!NBc) return;   // workspace too small for any config (diagnostic: bench will fail cleanly)
    int lTc = __builtin_ctz(Tc);

    float* ws  = (float*)d_ws;
    float* Wtg = ws;                                  // 4 * 192000
    float* Wts = Wtg + 768000;                        // 4 * 96000
    float* bsm = Wts + 384000;                        // 4 * 640
    float* hnb = bsm + 2560;                          // 256*150
    float* hst = hnb + 38400;                         // NBc*150
    float* cst = hst + (size_t)NBc * HIDN;            // NBc*150
    float* H   = cst + (size_t)NBc * HIDN;            // NBc*512*150
    float* G   = H   + (size_t)NBc * TT * HIDN;       // NBc*Tc*600

    int Kl[4] = {300, 150, 150, 150};
    for (int l = 0; l < 4; ++l) {
        int total = Kl[l] * NGP + HIDN * NGP + NGP;
        prep_kernel<<<(total + 255) / 256, 256, 0, stream>>>(
            Wih[l], Whh[l], bih[l], bhh[l], Kl[l],
            Wtg + l * 192000, Wts + l * 96000, bsm + l * 640);
    }

    int nTc = TT / Tc;
    int nBc = NBATCH / NBc;
    dim3 ggrid(NBc * Tc / MT, 5);
    for (int bc = 0; bc < nBc; ++bc) {
        int b_off = bc * NBc;
        for (int l = 0; l < 4; ++l) {
            for (int tc = 0; tc < nTc; ++tc) {
                int t0 = tc * Tc;
                gemm_kernel<<<ggrid, 256, 0, stream>>>(
                    H, (l == 0) ? x : nullptr, emb, Kl[l],
                    Wtg + l * 192000, bsm + l * 640, lengths, G, b_off, t0, lTc);
                scan_kernel<<<NBc / 2, 256, 0, stream>>>(
                    G, Wts + l * 96000, lengths, H, hnb, hst, cst, b_off, t0, Tc);
            }
        }
    }
    head_kernel<<<256, 256, 0, stream>>>(hnb, fc1_w, fc1_b, fc2_w, fc2_b, (float*)d_out);
}

// Round 3
// 8247.678 us; speedup vs baseline: 5.8623x; 5.8623x over previous
//
#include <hip/hip_runtime.h>

#define HIDN 150
#define NG   600     // 4*HIDN gates
#define NGP  640     // padded gate width (zero-padded in repacked weights)
#define TT   512
#define NBATCH 256

// ---------------- weight repack / bias prep ----------------
// Wtg: [K][640]   Wtg[k][n] = Wih[n][k]  (0 for n>=600)
// Wts: [150][640] Wts[k][n] = Whh[n][k]  (0 for n>=600)
// bsum[g] = bih[g]+bhh[g]
__global__ __launch_bounds__(256) void prep_kernel(
    const float* __restrict__ Wih, const float* __restrict__ Whh,
    const float* __restrict__ bih, const float* __restrict__ bhh,
    int K, float* __restrict__ Wtg, float* __restrict__ Wts,
    float* __restrict__ bsum)
{
    int i = blockIdx.x * 256 + threadIdx.x;
    int ngemm = K * NGP;
    if (i < ngemm) {
        int k = i / NGP, n = i % NGP;
        Wtg[i] = (n < NG) ? Wih[(size_t)n * K + k] : 0.f;
    } else if (i < ngemm + HIDN * NGP) {
        int j = i - ngemm;
        int k = j / NGP, n = j % NGP;
        Wts[j] = (n < NG) ? Whh[(size_t)n * HIDN + k] : 0.f;
    } else if (i < ngemm + HIDN * NGP + NGP) {
        int g = i - ngemm - HIDN * NGP;
        bsum[g] = (g < NG) ? (bih[g] + bhh[g]) : 0.f;
    }
}

// ---------------- x_proj GEMM ----------------
// Chunked: M rows = NBc*Tc laid out [bb][tloc]; row rg -> bb=rg>>lTc, tloc=rg&(Tc-1).
// A (H buffer) is [NBc][512][150]; C (G chunk) is [NBc*Tc][600] chunk-linear.
#define MT 128
#define NT 128
#define KT 32

__global__ __launch_bounds__(256) void gemm_kernel(
    const float* __restrict__ A,       // H buffer [NBc][512][150] (layers 1-3) or nullptr
    const int*   __restrict__ gather,  // x indices (layer 0) or nullptr
    const float* __restrict__ emb,     // [50000][300]
    int K,
    const float* __restrict__ Bt,      // [K][640] repacked W^T
    const float* __restrict__ bsum,    // [640]
    const int*   __restrict__ lengths,
    float* __restrict__ C,             // [NBc*Tc][600]
    int b_off, int t0, int lTc)
{
    int Tcm1 = (1 << lTc) - 1;
    int m0 = blockIdx.x * MT;
    int n0 = blockIdx.y * NT;
    if (lTc >= 7) {                    // tile lies within a single batch: early skip
        int b = b_off + (m0 >> lTc);
        int tmax = lengths[b];                        // per-batch: scan b never reads t >= len[b]
        if (t0 + (m0 & Tcm1) >= tmax) return;
    }

    __shared__ __align__(16) float As[MT][36];    // stride 36: f4-aligned, breaks ty conflicts
    __shared__ __align__(16) float Bs[KT][NT];

    int tid = threadIdx.x;
    int tx = tid & 15, ty = tid >> 4;

    float acc[8][8];
    #pragma unroll
    for (int i = 0; i < 8; ++i)
        #pragma unroll
        for (int j = 0; j < 8; ++j) acc[i][j] = 0.f;

    for (int k0 = 0; k0 < K; k0 += KT) {
        #pragma unroll
        for (int it = 0; it < 16; ++it) {
            int idx = it * 256 + tid;
            int c = idx & (KT - 1), r = idx >> 5;
            int kk = k0 + c;
            float v = 0.f;
            if (kk < K) {
                int rg = m0 + r;
                int bb = rg >> lTc, tl = rg & Tcm1;
                const float* row = gather
                    ? (emb + (size_t)gather[(b_off + bb) * TT + t0 + tl] * 300)
                    : (A + ((size_t)bb * TT + t0 + tl) * HIDN);
                v = row[kk];
            }
            As[r][c] = v;
        }
        #pragma unroll
        for (int it = 0; it < 16; ++it) {
            int idx = it * 256 + tid;
            int n = idx & (NT - 1), kk = idx >> 7;
            Bs[kk][n] = (k0 + kk < K) ? Bt[(size_t)(k0 + kk) * NGP + n0 + n] : 0.f;
        }
        __syncthreads();
        #pragma unroll
        for (int k4 = 0; k4 < KT / 4; ++k4) {
            float a4[8][4];
            #pragma unroll
            for (int i = 0; i < 8; ++i) {
                float4 t4 = *(const float4*)&As[ty + 16 * i][k4 * 4];
                a4[i][0] = t4.x; a4[i][1] = t4.y; a4[i][2] = t4.z; a4[i][3] = t4.w;
            }
            #pragma unroll
            for (int kk = 0; kk < 4; ++kk) {
                float4 bA = *(const float4*)&Bs[k4 * 4 + kk][tx * 8];
                float4 bB = *(const float4*)&Bs[k4 * 4 + kk][tx * 8 + 4];
                float bv[8] = {bA.x, bA.y, bA.z, bA.w, bB.x, bB.y, bB.z, bB.w};
                #pragma unroll
                for (int i = 0; i < 8; ++i) {
                    float a = a4[i][kk];
                    #pragma unroll
                    for (int j = 0; j < 8; ++j) acc[i][j] += a * bv[j];
                }
            }
        }
        __syncthreads();
    }

    int n = n0 + tx * 8;
    float4 bs1 = *(const float4*)&bsum[n];
    float4 bs2 = *(const float4*)&bsum[n + 4];
    #pragma unroll
    for (int i = 0; i < 8; ++i) {
        float* crow = C + (size_t)(m0 + ty + 16 * i) * NG;
        if (n < NG) {
            float4 v = make_float4(acc[i][0] + bs1.x, acc[i][1] + bs1.y,
                                   acc[i][2] + bs1.z, acc[i][3] + bs1.w);
            *(float4*)&crow[n] = v;
        }
        if (n + 4 < NG) {
            float4 v = make_float4(acc[i][4] + bs2.x, acc[i][5] + bs2.y,
                                   acc[i][6] + bs2.z, acc[i][7] + bs2.w);
            *(float4*)&crow[n + 4] = v;
        }
    }
}

// ---------------- recurrent scan: weight-stationary, one block per batch ----------------
// 640 threads; thread n owns gate column n. Whh^T k<128 in 128 VGPRs, k=128..149 in LDS.
// Hot loop: zero global weight traffic; h broadcast via LDS.
#define REGK  32    // 32 float4 = k 0..127
#define TAILP 11    // 11 float2 pairs = k 128..149

__global__ __launch_bounds__(640) void scan_kernel(
    const float* __restrict__ G,       // [NBc][Tc][600] chunk of x_proj+bias
    const float* __restrict__ Wt,      // [150][640] Whh^T padded
    const int*   __restrict__ lengths,
    float* __restrict__ H,             // [NBc][512][150] in-place layer output
    float* __restrict__ hnb,           // [256][150] last-h capture (global batch idx)
    float* __restrict__ hst,           // [NBc][150] h carry
    float* __restrict__ cst,           // [NBc][150] c carry
    int b_off, int t0, int Tc)
{
    __shared__ __align__(16) float h_s[152];
    __shared__ float gate_s[NG];
    __shared__ __align__(8) float wl2[TAILP][NGP][2];   // 56.3 KB

    int tid = threadIdx.x;
    int l0 = blockIdx.x;
    int b  = b_off + l0;
    int len = lengths[b];
    int tmax = min(len, t0 + Tc);

    // --- one-time weight residency (k<128 -> VGPRs, coalesced column loads) ---
    float4 wr[REGK];
    #pragma unroll
    for (int q = 0; q < REGK; ++q) {
        wr[q].x = Wt[(4 * q + 0) * NGP + tid];
        wr[q].y = Wt[(4 * q + 1) * NGP + tid];
        wr[q].z = Wt[(4 * q + 2) * NGP + tid];
        wr[q].w = Wt[(4 * q + 3) * NGP + tid];
    }
    #pragma unroll
    for (int p = 0; p < TAILP; ++p) {
        wl2[p][tid][0] = Wt[(128 + 2 * p) * NGP + tid];
        wl2[p][tid][1] = Wt[(129 + 2 * p) * NGP + tid];
    }

    float c = 0.f;
    if (tid < 152) h_s[tid] = 0.f;
    if (tid < HIDN && t0 > 0) {
        h_s[tid] = hst[l0 * HIDN + tid];
        c = cst[l0 * HIDN + tid];
    }

    bool isg    = (tid >= 2 * HIDN) && (tid < 3 * HIDN);   // g-gate -> tanh
    bool act600 = (tid < NG);
    const float* Gbase = G + (size_t)l0 * Tc * NG + tid;
    __syncthreads();

    for (int t = t0; t < tmax; ++t) {
        float gval = act600 ? Gbase[(size_t)(t - t0) * NG] : 0.f;  // overlapped with dot
        float acc = 0.f;
        #pragma unroll
        for (int q = 0; q < REGK; ++q) {
            float4 h4 = *(const float4*)&h_s[4 * q];               // LDS broadcast
            acc += wr[q].x * h4.x; acc += wr[q].y * h4.y;
            acc += wr[q].z * h4.z; acc += wr[q].w * h4.w;
        }
        #pragma unroll
        for (int p = 0; p < TAILP; ++p) {
            float2 wp = *(const float2*)&wl2[p][tid][0];
            float2 hp = *(const float2*)&h_s[128 + 2 * p];
            acc += wp.x * hp.x; acc += wp.y * hp.y;
        }
        float a = gval + acc;
        // branch-free sigmoid / tanh (tanh(a) = 2*sigmoid(2a)-1), one exp each
        float bb = isg ? 2.f * a : a;
        float e  = __expf(-bb);
        float r  = 1.f / (1.f + e);
        a = isg ? 2.f * r - 1.f : r;
        if (act600) gate_s[tid] = a;
        __syncthreads();
        if (tid < HIDN) {
            float iv = gate_s[tid];
            float fv = gate_s[tid + HIDN];
            float gv = gate_s[tid + 2 * HIDN];
            float ov = gate_s[tid + 3 * HIDN];
            float cn = fv * c + iv * gv;
            float e2 = __expf(-2.f * cn);
            float th = 2.f / (1.f + e2) - 1.f;
            float hv = ov * th;
            c = cn;
            h_s[tid] = hv;
            H[((size_t)l0 * TT + t) * HIDN + tid] = hv;   // only t<len written; t>=len never read
            if (t == len - 1) hnb[b * HIDN + tid] = hv;
        }
        __syncthreads();
    }

    if (tid < HIDN) {
        hst[l0 * HIDN + tid] = h_s[tid];
        cst[l0 * HIDN + tid] = c;
    }
}

// ---------------- fc1+relu+fc2 head ----------------
__global__ __launch_bounds__(256) void head_kernel(
    const float* __restrict__ hnb, const float* __restrict__ fc1_w,
    const float* __restrict__ fc1_b, const float* __restrict__ fc2_w,
    const float* __restrict__ fc2_b, float* __restrict__ out)
{
    __shared__ float hs[HIDN];
    __shared__ float zs[HIDN];
    int b = blockIdx.x, tid = threadIdx.x;
    if (tid < HIDN) hs[tid] = hnb[b * HIDN + tid];
    __syncthreads();
    if (tid < HIDN) {
        float acc = fc1_b[tid];
        const float* wr = fc1_w + (size_t)tid * HIDN;
        #pragma unroll 5
        for (int k = 0; k < HIDN; ++k) acc += wr[k] * hs[k];
        zs[tid] = fmaxf(acc, 0.f);
    }
    __syncthreads();
    if (tid == 0) {
        float s = fc2_b[0];
        for (int k = 0; k < HIDN; ++k) s += fc2_w[k] * zs[k];
        out[b] = s;
    }
}

extern "C" void kernel_launch(void* const* d_in, const int* in_sizes, int n_in,
                              void* d_out, int out_size, void* d_ws, size_t ws_size,
                              hipStream_t stream)
{
    const int*   x       = (const int*)d_in[0];
    const int*   lengths = (const int*)d_in[1];
    const float* emb     = (const float*)d_in[2];
    const float *Wih[4], *Whh[4], *bih[4], *bhh[4];
    for (int l = 0; l < 4; ++l) {
        Wih[l] = (const float*)d_in[3 + 4 * l];
        Whh[l] = (const float*)d_in[4 + 4 * l];
        bih[l] = (const float*)d_in[5 + 4 * l];
        bhh[l] = (const float*)d_in[6 + 4 * l];
    }
    const float* fc1_w = (const float*)d_in[19];
    const float* fc1_b = (const float*)d_in[20];
    const float* fc2_w = (const float*)d_in[21];
    const float* fc2_b = (const float*)d_in[22];

    // ---- adaptive workspace sizing (ws_size is constant across calls -> graph-safe) ----
    size_t wf = ws_size / sizeof(float);
    const size_t WFIX = 768000 + 384000 + 2560 + 38400;   // Wtg + Wts + bsm + hnb
    int NBc = 0, Tc = 0;
    for (int nb = 256; nb >= 16; nb >>= 1) {
        for (int tc = 512; tc >= 8; tc >>= 1) {
            size_t need = WFIX + (size_t)nb * 2 * HIDN          // h/c carry
                        + (size_t)nb * TT * HIDN                 // H (single, in-place)
                        + (size_t)nb * tc * NG;                  // G chunk
            if (need <= wf) { NBc = nb; Tc = tc; break; }
        }
        if (NBc) break;
    }
    if (!NBc) return;
    int lTc = __builtin_ctz(Tc);

    float* ws  = (float*)d_ws;
    float* Wtg = ws;                                  // 4 * 192000
    float* Wts = Wtg + 768000;                        // 4 * 96000
    float* bsm = Wts + 384000;                        // 4 * 640
    float* hnb = bsm + 2560;                          // 256*150
    float* hst = hnb + 38400;                         // NBc*150
    float* cst = hst + (size_t)NBc * HIDN;            // NBc*150
    float* H   = cst + (size_t)NBc * HIDN;            // NBc*512*150
    float* G   = H   + (size_t)NBc * TT * HIDN;       // NBc*Tc*600

    int Kl[4] = {300, 150, 150, 150};
    for (int l = 0; l < 4; ++l) {
        int total = Kl[l] * NGP + HIDN * NGP + NGP;
        prep_kernel<<<(total + 255) / 256, 256, 0, stream>>>(
            Wih[l], Whh[l], bih[l], bhh[l], Kl[l],
            Wtg + l * 192000, Wts + l * 96000, bsm + l * 640);
    }

    int nTc = TT / Tc;
    int nBc = NBATCH / NBc;
    dim3 ggrid(NBc * Tc / MT, 5);
    for (int bc = 0; bc < nBc; ++bc) {
        int b_off = bc * NBc;
        for (int l = 0; l < 4; ++l) {
            for (int tc = 0; tc < nTc; ++tc) {
                int t0 = tc * Tc;
                gemm_kernel<<<ggrid, 256, 0, stream>>>(
                    H, (l == 0) ? x : nullptr, emb, Kl[l],
                    Wtg + l * 192000, bsm + l * 640, lengths, G, b_off, t0, lTc);
                scan_kernel<<<NBc, 640, 0, stream>>>(
                    G, Wts + l * 96000, lengths, H, hnb, hst, cst, b_off, t0, Tc);
            }
        }
    }
    head_kernel<<<256, 256, 0, stream>>>(hnb, fc1_w, fc1_b, fc2_w, fc2_b, (float*)d_out);
}

// Round 4
// 3363.842 us; speedup vs baseline: 14.3736x; 2.4519x over previous
//
#include <hip/hip_runtime.h>

#define HIDN 150
#define NG   600     // 4*HIDN gates
#define NGP  640     // padded gate width
#define TT   512
#define NBATCH 256
#define KPA  160     // padded K for H->next-layer A buffers
#define KPE  320     // padded K for embedding

typedef __attribute__((ext_vector_type(8))) short bf16x8;
typedef __attribute__((ext_vector_type(4))) float f32x4;

__device__ __forceinline__ unsigned short f2bf(float v) {
    unsigned int u = __builtin_bit_cast(unsigned int, v);
    u += 0x7fffu + ((u >> 16) & 1u);          // RNE
    return (unsigned short)(u >> 16);
}
__device__ __forceinline__ float bf2f(unsigned short h) {
    unsigned int u = ((unsigned int)h) << 16;
    return __builtin_bit_cast(float, u);
}

#define GLDS(gp, lp) __builtin_amdgcn_global_load_lds( \
    (const __attribute__((address_space(1))) unsigned int*)(gp), \
    (__attribute__((address_space(3))) unsigned int*)(lp), 16, 0, 0)

// ---------------- embedding split: emb[50000][300] fp32 -> embh/embl [50000][320] bf16 ----------------
__global__ __launch_bounds__(256) void embprep_kernel(
    const float* __restrict__ emb,
    unsigned short* __restrict__ eh, unsigned short* __restrict__ el)
{
    int i = blockIdx.x * 256 + threadIdx.x;
    if (i >= 50000 * KPE) return;
    int v = i / KPE, k = i - v * KPE;
    float x = (k < 300) ? emb[(size_t)v * 300 + k] : 0.f;
    unsigned short hi = f2bf(x);
    eh[i] = hi;
    el[i] = f2bf(x - bf2f(hi));
}

// ---------------- per-layer weight prep ----------------
// Wgh/Wgl: [640][Kp] bf16 hi/lo of Wih (n>=600 or k>=K -> 0)   [n][k] layout = MFMA B^T
// Wts:     [150][640] fp32 Whh^T padded (scan weights)
// bsum:    [640] fp32 bih+bhh
__global__ __launch_bounds__(256) void prep_kernel(
    const float* __restrict__ Wih, const float* __restrict__ Whh,
    const float* __restrict__ bih, const float* __restrict__ bhh,
    int K, int Kp,
    unsigned short* __restrict__ Wgh, unsigned short* __restrict__ Wgl,
    float* __restrict__ Wts, float* __restrict__ bsum)
{
    int i = blockIdx.x * 256 + threadIdx.x;
    int nW = NGP * Kp;
    if (i < nW) {
        int n = i / Kp, k = i - n * Kp;
        float w = (n < NG && k < K) ? Wih[(size_t)n * K + k] : 0.f;
        unsigned short hi = f2bf(w);
        Wgh[i] = hi;
        Wgl[i] = f2bf(w - bf2f(hi));
    } else if (i < nW + HIDN * NGP) {
        int j = i - nW;
        int k = j / NGP, n = j - k * NGP;
        Wts[j] = (n < NG) ? Whh[(size_t)n * HIDN + k] : 0.f;
    } else if (i < nW + HIDN * NGP + NGP) {
        int g = i - nW - HIDN * NGP;
        bsum[g] = (g < NG) ? (bih[g] + bhh[g]) : 0.f;
    }
}

// ---------------- x_proj GEMM: split-bf16 MFMA ----------------
// C[m][n] = sum_k A[m][k]*W[n][k] + bsum[n], A = hi/lo bf16 (gathered emb for layer 0),
// W = hi/lo bf16 [640][Kp]. 128x128 tile, 4 waves x (4x4) subtiles of 16x16x32.
// 3 MFMAs per subtile-kstep: ah*bh + ah*bl + al*bh into one fp32 acc.
__global__ __launch_bounds__(256, 2) void gemm_kernel(
    const unsigned short* __restrict__ Ah, const unsigned short* __restrict__ Al, // [NBc][512][160] or null
    const int* __restrict__ gather,                                               // layer-0 x or null
    const unsigned short* __restrict__ Eh, const unsigned short* __restrict__ El, // emb split
    int Kp,
    const unsigned short* __restrict__ Wh, const unsigned short* __restrict__ Wl, // [640][Kp]
    const float* __restrict__ bsum, const int* __restrict__ lengths,
    float* __restrict__ G,                                                        // [NBc*Tc][600]
    int b_off, int t0, int lTc)
{
    int m0 = blockIdx.x * 128;
    int n0 = blockIdx.y * 128;
    int Tcm1 = (1 << lTc) - 1;
    if (lTc >= 7) {                               // tile within one batch: early skip
        int b = b_off + (m0 >> lTc);
        if (t0 + (m0 & Tcm1) >= lengths[b]) return;
    }

    __shared__ __align__(16) unsigned short Ash[128][32];
    __shared__ __align__(16) unsigned short Asl[128][32];
    __shared__ __align__(16) unsigned short Bsh[128][32];
    __shared__ __align__(16) unsigned short Bsl[128][32];

    int tid = threadIdx.x, lane = tid & 63, wave = tid >> 6;

    // row base offsets (fixed across k)
    const unsigned short* AhB = gather ? Eh : Ah;
    const unsigned short* AlB = gather ? El : Al;
    size_t ra[2], rb[2];
    int mrow[2];
    #pragma unroll
    for (int c2 = 0; c2 < 2; ++c2) {
        int mb = wave * 32 + c2 * 16;
        mrow[c2] = mb;
        int rg = m0 + mb + (lane >> 2);
        int bb = rg >> lTc, tl = rg & Tcm1;
        ra[c2] = gather ? (size_t)gather[(b_off + bb) * TT + t0 + tl] * (size_t)Kp
                        : ((size_t)bb * TT + t0 + tl) * (size_t)Kp;
        int nr = n0 + mb + (lane >> 2);
        rb[c2] = (size_t)nr * (size_t)Kp;
    }
    int klane = (lane & 3) * 8;

    f32x4 acc[4][4];
    #pragma unroll
    for (int i = 0; i < 4; ++i)
        #pragma unroll
        for (int j = 0; j < 4; ++j) acc[i][j] = (f32x4){0.f, 0.f, 0.f, 0.f};

    int fr = (lane >> 4) * 8;      // k offset inside fragment
    int ml = lane & 15;
    int mbase = (wave & 1) * 64;   // this wave's m-subtile origin (4 subtiles)
    int nbase = (wave >> 1) * 64;  // this wave's n-subtile origin

    for (int k0 = 0; k0 < Kp; k0 += 32) {
        #pragma unroll
        for (int c2 = 0; c2 < 2; ++c2) {
            GLDS(AhB + ra[c2] + k0 + klane, &Ash[mrow[c2]][0]);
            GLDS(AlB + ra[c2] + k0 + klane, &Asl[mrow[c2]][0]);
            GLDS(Wh  + rb[c2] + k0 + klane, &Bsh[mrow[c2]][0]);
            GLDS(Wl  + rb[c2] + k0 + klane, &Bsl[mrow[c2]][0]);
        }
        __syncthreads();

        bf16x8 afh[4], afl[4], bfh[4], bfl[4];
        #pragma unroll
        for (int i = 0; i < 4; ++i) {
            afh[i] = *(const bf16x8*)&Ash[mbase + i * 16 + ml][fr];
            afl[i] = *(const bf16x8*)&Asl[mbase + i * 16 + ml][fr];
            bfh[i] = *(const bf16x8*)&Bsh[nbase + i * 16 + ml][fr];
            bfl[i] = *(const bf16x8*)&Bsl[nbase + i * 16 + ml][fr];
        }
        #pragma unroll
        for (int i = 0; i < 4; ++i)
            #pragma unroll
            for (int j = 0; j < 4; ++j)
                acc[i][j] = __builtin_amdgcn_mfma_f32_16x16x32_bf16(afh[i], bfh[j], acc[i][j], 0, 0, 0);
        #pragma unroll
        for (int i = 0; i < 4; ++i)
            #pragma unroll
            for (int j = 0; j < 4; ++j)
                acc[i][j] = __builtin_amdgcn_mfma_f32_16x16x32_bf16(afh[i], bfl[j], acc[i][j], 0, 0, 0);
        #pragma unroll
        for (int i = 0; i < 4; ++i)
            #pragma unroll
            for (int j = 0; j < 4; ++j)
                acc[i][j] = __builtin_amdgcn_mfma_f32_16x16x32_bf16(afl[i], bfh[j], acc[i][j], 0, 0, 0);
        __syncthreads();
    }

    // epilogue: C/D layout col=lane&15, row=(lane>>4)*4+r  (m89-verified)
    int rq = lane >> 4;
    #pragma unroll
    for (int i = 0; i < 4; ++i) {
        int mg = m0 + mbase + i * 16 + rq * 4;
        #pragma unroll
        for (int j = 0; j < 4; ++j) {
            int ng = n0 + nbase + j * 16 + ml;
            if (ng < NG) {
                float bz = bsum[ng];
                #pragma unroll
                for (int r = 0; r < 4; ++r)
                    G[(size_t)(mg + r) * NG + ng] = acc[i][j][r] + bz;
            }
        }
    }
}

// ---------------- recurrent scan: weight-stationary, one block per batch ----------------
// 640 threads; thread n owns gate column n. Whh^T k<128 in 128 VGPRs, k=128..149 in LDS.
// Emits h as split hi/lo bf16 [NBc][512][160] for the next layer's MFMA GEMM.
#define REGK  32
#define TAILP 11

__global__ __launch_bounds__(640) void scan_kernel(
    const float* __restrict__ G,       // [NBc][Tc][600]
    const float* __restrict__ Wt,      // [150][640] Whh^T padded
    const int*   __restrict__ lengths,
    unsigned short* __restrict__ Aout, // [NBc][512][160] bf16-hi h, or null (layer 3)
    unsigned short* __restrict__ Alout,// bf16-lo h
    float* __restrict__ hnb,           // [256][150] last-h capture
    float* __restrict__ hst, float* __restrict__ cst,   // [NBc][150] carries
    int b_off, int t0, int Tc)
{
    __shared__ __align__(16) float h_s[152];
    __shared__ float gate_s[NG];
    __shared__ __align__(8) float wl2[TAILP][NGP][2];

    int tid = threadIdx.x;
    int l0 = blockIdx.x;
    int b  = b_off + l0;
    int len = lengths[b];
    int tmax = min(len, t0 + Tc);

    float4 wr[REGK];
    #pragma unroll
    for (int q = 0; q < REGK; ++q) {
        wr[q].x = Wt[(4 * q + 0) * NGP + tid];
        wr[q].y = Wt[(4 * q + 1) * NGP + tid];
        wr[q].z = Wt[(4 * q + 2) * NGP + tid];
        wr[q].w = Wt[(4 * q + 3) * NGP + tid];
    }
    #pragma unroll
    for (int p = 0; p < TAILP; ++p) {
        wl2[p][tid][0] = Wt[(128 + 2 * p) * NGP + tid];
        wl2[p][tid][1] = Wt[(129 + 2 * p) * NGP + tid];
    }

    float c = 0.f;
    if (tid < 152) h_s[tid] = 0.f;
    if (tid < HIDN && t0 > 0) {
        h_s[tid] = hst[l0 * HIDN + tid];
        c = cst[l0 * HIDN + tid];
    }

    bool isg    = (tid >= 2 * HIDN) && (tid < 3 * HIDN);
    bool act600 = (tid < NG);
    const float* Gbase = G + (size_t)l0 * Tc * NG + tid;
    __syncthreads();

    for (int t = t0; t < tmax; ++t) {
        float gval = act600 ? Gbase[(size_t)(t - t0) * NG] : 0.f;
        float acc = 0.f;
        #pragma unroll
        for (int q = 0; q < REGK; ++q) {
            float4 h4 = *(const float4*)&h_s[4 * q];
            acc += wr[q].x * h4.x; acc += wr[q].y * h4.y;
            acc += wr[q].z * h4.z; acc += wr[q].w * h4.w;
        }
        #pragma unroll
        for (int p = 0; p < TAILP; ++p) {
            float2 wp = *(const float2*)&wl2[p][tid][0];
            float2 hp = *(const float2*)&h_s[128 + 2 * p];
            acc += wp.x * hp.x; acc += wp.y * hp.y;
        }
        float a = gval + acc;
        float bb = isg ? 2.f * a : a;
        float e  = __expf(-bb);
        float r  = 1.f / (1.f + e);
        a = isg ? 2.f * r - 1.f : r;
        if (act600) gate_s[tid] = a;
        __syncthreads();
        if (tid < KPA) {
            float hv = 0.f;
            if (tid < HIDN) {
                float iv = gate_s[tid];
                float fv = gate_s[tid + HIDN];
                float gv = gate_s[tid + 2 * HIDN];
                float ov = gate_s[tid + 3 * HIDN];
                float cn = fv * c + iv * gv;
                float e2 = __expf(-2.f * cn);
                float th = 2.f / (1.f + e2) - 1.f;
                hv = ov * th;
                c = cn;
                h_s[tid] = hv;
                if (t == len - 1) hnb[b * HIDN + tid] = hv;
            }
            if (Aout) {
                size_t off = ((size_t)l0 * TT + t) * KPA + tid;
                unsigned short hi = f2bf(hv);
                Aout[off]  = hi;
                Alout[off] = f2bf(hv - bf2f(hi));
            }
        }
        __syncthreads();
    }

    if (tid < HIDN) {
        hst[l0 * HIDN + tid] = h_s[tid];
        cst[l0 * HIDN + tid] = c;
    }
}

// ---------------- fc1+relu+fc2 head ----------------
__global__ __launch_bounds__(256) void head_kernel(
    const float* __restrict__ hnb, const float* __restrict__ fc1_w,
    const float* __restrict__ fc1_b, const float* __restrict__ fc2_w,
    const float* __restrict__ fc2_b, float* __restrict__ out)
{
    __shared__ float hs[HIDN];
    __shared__ float zs[HIDN];
    int b = blockIdx.x, tid = threadIdx.x;
    if (tid < HIDN) hs[tid] = hnb[b * HIDN + tid];
    __syncthreads();
    if (tid < HIDN) {
        float acc = fc1_b[tid];
        const float* wr = fc1_w + (size_t)tid * HIDN;
        #pragma unroll 5
        for (int k = 0; k < HIDN; ++k) acc += wr[k] * hs[k];
        zs[tid] = fmaxf(acc, 0.f);
    }
    __syncthreads();
    if (tid == 0) {
        float s = fc2_b[0];
        for (int k = 0; k < HIDN; ++k) s += fc2_w[k] * zs[k];
        out[b] = s;
    }
}

extern "C" void kernel_launch(void* const* d_in, const int* in_sizes, int n_in,
                              void* d_out, int out_size, void* d_ws, size_t ws_size,
                              hipStream_t stream)
{
    const int*   x       = (const int*)d_in[0];
    const int*   lengths = (const int*)d_in[1];
    const float* emb     = (const float*)d_in[2];
    const float *Wih[4], *Whh[4], *bih[4], *bhh[4];
    for (int l = 0; l < 4; ++l) {
        Wih[l] = (const float*)d_in[3 + 4 * l];
        Whh[l] = (const float*)d_in[4 + 4 * l];
        bih[l] = (const float*)d_in[5 + 4 * l];
        bhh[l] = (const float*)d_in[6 + 4 * l];
    }
    const float* fc1_w = (const float*)d_in[19];
    const float* fc1_b = (const float*)d_in[20];
    const float* fc2_w = (const float*)d_in[21];
    const float* fc2_b = (const float*)d_in[22];

    int Kl[4]  = {300, 150, 150, 150};
    int Kp[4]  = {KPE, KPA, KPA, KPA};
    size_t wgoff[4];   // ushort offsets of per-layer hi block (lo follows)
    size_t wgacc = 0;
    for (int l = 0; l < 4; ++l) { wgoff[l] = wgacc; wgacc += 2 * (size_t)NGP * Kp[l]; }
    // wgacc = 1,024,000 ushorts = 512,000 floats

    // ---- adaptive workspace sizing ----
    size_t wf = ws_size / sizeof(float);
    const size_t WFIX = 384000 + 2560 + 38400 + 512000 + 16000000; // Wts+bsm+hnb+Wg+embsplit
    int NBc = 0, Tc = 0;
    for (int nb = 256; nb >= 16; nb >>= 1) {
        for (int tc = 512; tc >= 8; tc >>= 1) {
            size_t need = WFIX + (size_t)nb * 300                 // h/c carry
                        + (size_t)nb * TT * (2 * KPA / 2)         // Ah+Al bf16 = nb*81920 floats
                        + (size_t)nb * tc * NG;                   // G chunk
            if (need <= wf) { NBc = nb; Tc = tc; break; }
        }
        if (NBc) break;
    }
    if (!NBc) return;
    int lTc = __builtin_ctz(Tc);

    float* ws  = (float*)d_ws;
    float* Wts = ws;                                    // 4 * 96000
    float* bsm = Wts + 384000;                          // 4 * 640
    float* hnb = bsm + 2560;                            // 256*150
    unsigned short* Wg = (unsigned short*)(hnb + 38400);        // 1,024,000 ushorts
    unsigned short* embh = Wg + 1024000;                        // 16,000,000 ushorts
    unsigned short* embl = embh + 16000000;                     // 16,000,000 ushorts
    float* hst = (float*)(embl + 16000000);             // NBc*150
    float* cst = hst + (size_t)NBc * HIDN;              // NBc*150
    unsigned short* Ahh = (unsigned short*)(cst + (size_t)NBc * HIDN);  // NBc*512*160
    unsigned short* Ahl = Ahh + (size_t)NBc * TT * KPA;                 // NBc*512*160
    float* G   = (float*)(Ahl + (size_t)NBc * TT * KPA);                // NBc*Tc*600

    embprep_kernel<<<(50000 * KPE + 255) / 256, 256, 0, stream>>>(emb, embh, embl);
    for (int l = 0; l < 4; ++l) {
        int total = NGP * Kp[l] + HIDN * NGP + NGP;
        prep_kernel<<<(total + 255) / 256, 256, 0, stream>>>(
            Wih[l], Whh[l], bih[l], bhh[l], Kl[l], Kp[l],
            Wg + wgoff[l], Wg + wgoff[l] + (size_t)NGP * Kp[l],
            Wts + l * 96000, bsm + l * 640);
    }

    int nTc = TT / Tc;
    int nBc = NBATCH / NBc;
    dim3 ggrid((unsigned)(NBc * Tc / 128), 5);
    for (int bc = 0; bc < nBc; ++bc) {
        int b_off = bc * NBc;
        for (int l = 0; l < 4; ++l) {
            const unsigned short* Wh = Wg + wgoff[l];
            const unsigned short* Wl = Wh + (size_t)NGP * Kp[l];
            for (int tc = 0; tc < nTc; ++tc) {
                int t0 = tc * Tc;
                gemm_kernel<<<ggrid, 256, 0, stream>>>(
                    (l == 0) ? nullptr : Ahh, (l == 0) ? nullptr : Ahl,
                    (l == 0) ? x : nullptr, embh, embl,
                    Kp[l], Wh, Wl, bsm + l * 640, lengths, G, b_off, t0, lTc);
                scan_kernel<<<NBc, 640, 0, stream>>>(
                    G, Wts + l * 96000, lengths,
                    (l == 3) ? nullptr : Ahh, (l == 3) ? nullptr : Ahl,
                    hnb, hst, cst, b_off, t0, Tc);
            }
        }
    }
    head_kernel<<<256, 256, 0, stream>>>(hnb, fc1_w, fc1_b, fc2_w, fc2_b, (float*)d_out);
}

// Round 5
// 3344.008 us; speedup vs baseline: 14.4588x; 1.0059x over previous
//
#include <hip/hip_runtime.h>

#define HIDN 150
#define NG   600     // 4*HIDN gates
#define NGP  640     // padded gate width / G row stride / scan slot count
#define TT   512
#define NBATCH 256
#define KPA  160     // padded K for H->next-layer A buffers
#define KPE  320     // padded K for embedding

typedef __attribute__((ext_vector_type(8))) short bf16x8;
typedef __attribute__((ext_vector_type(4))) float f32x4;

__device__ __forceinline__ unsigned short f2bf(float v) {
    unsigned int u = __builtin_bit_cast(unsigned int, v);
    u += 0x7fffu + ((u >> 16) & 1u);          // RNE
    return (unsigned short)(u >> 16);
}
__device__ __forceinline__ float bf2f(unsigned short h) {
    unsigned int u = ((unsigned int)h) << 16;
    return __builtin_bit_cast(float, u);
}

#define GLDS(gp, lp) __builtin_amdgcn_global_load_lds( \
    (const __attribute__((address_space(1))) unsigned int*)(gp), \
    (__attribute__((address_space(3))) unsigned int*)(lp), 16, 0, 0)

// scan slot for gate column n (n<600): u=n%150, g=n/150 -> s = (u>>4)*64 + g*16 + (u&15)
__device__ __forceinline__ int slot_of(int n) {
    int g = n / HIDN, u = n - g * HIDN;
    return ((u >> 4) << 6) + (g << 4) + (u & 15);
}

// ---------------- embedding split: emb[50000][300] fp32 -> embh/embl [50000][320] bf16 ----------------
__global__ __launch_bounds__(256) void embprep_kernel(
    const float* __restrict__ emb,
    unsigned short* __restrict__ eh, unsigned short* __restrict__ el)
{
    int i = blockIdx.x * 256 + threadIdx.x;
    if (i >= 50000 * KPE) return;
    int v = i / KPE, k = i - v * KPE;
    float x = (k < 300) ? emb[(size_t)v * 300 + k] : 0.f;
    unsigned short hi = f2bf(x);
    eh[i] = hi;
    el[i] = f2bf(x - bf2f(hi));
}

// ---------------- per-layer weight prep ----------------
// Wgh/Wgl: [640][Kp] bf16 hi/lo of Wih; Wts: [150][640] fp32 Whh^T in PERMUTED slot order;
// bsum: [640] fp32 bih+bhh (original column order; consumed by gemm epilogue).
__global__ __launch_bounds__(256) void prep_kernel(
    const float* __restrict__ Wih, const float* __restrict__ Whh,
    const float* __restrict__ bih, const float* __restrict__ bhh,
    int K, int Kp,
    unsigned short* __restrict__ Wgh, unsigned short* __restrict__ Wgl,
    float* __restrict__ Wts, float* __restrict__ bsum)
{
    int i = blockIdx.x * 256 + threadIdx.x;
    int nW = NGP * Kp;
    if (i < nW) {
        int n = i / Kp, k = i - n * Kp;
        float w = (n < NG && k < K) ? Wih[(size_t)n * K + k] : 0.f;
        unsigned short hi = f2bf(w);
        Wgh[i] = hi;
        Wgl[i] = f2bf(w - bf2f(hi));
    } else if (i < nW + HIDN * NGP) {
        int j = i - nW;
        int k = j / NGP, s = j - k * NGP;
        // invert slot: s -> (w,l) -> u = (s>>6)*16 + (s&15), g = (s>>4)&3
        int u = ((s >> 6) << 4) + (s & 15);
        int g = (s >> 4) & 3;
        Wts[j] = (u < HIDN) ? Whh[(size_t)(g * HIDN + u) * HIDN + k] : 0.f;
    } else if (i < nW + HIDN * NGP + NGP) {
        int g = i - nW - HIDN * NGP;
        bsum[g] = (g < NG) ? (bih[g] + bhh[g]) : 0.f;
    }
}

// ---------------- x_proj GEMM: split-bf16 MFMA ----------------
// G written in PERMUTED slot order, row stride 640 (scan reads G[row][tid] coalesced).
__global__ __launch_bounds__(256, 2) void gemm_kernel(
    const unsigned short* __restrict__ Ah, const unsigned short* __restrict__ Al,
    const int* __restrict__ gather,
    const unsigned short* __restrict__ Eh, const unsigned short* __restrict__ El,
    int Kp,
    const unsigned short* __restrict__ Wh, const unsigned short* __restrict__ Wl,
    const float* __restrict__ bsum, const int* __restrict__ lengths,
    float* __restrict__ G,                                       // [NBc*Tc][640] permuted
    int b_off, int t0, int lTc)
{
    int m0 = blockIdx.x * 128;
    int n0 = blockIdx.y * 128;
    int Tcm1 = (1 << lTc) - 1;
    if (lTc >= 7) {
        int b = b_off + (m0 >> lTc);
        if (t0 + (m0 & Tcm1) >= lengths[b]) return;
    }

    __shared__ __align__(16) unsigned short Ash[128][32];
    __shared__ __align__(16) unsigned short Asl[128][32];
    __shared__ __align__(16) unsigned short Bsh[128][32];
    __shared__ __align__(16) unsigned short Bsl[128][32];

    int tid = threadIdx.x, lane = tid & 63, wave = tid >> 6;

    const unsigned short* AhB = gather ? Eh : Ah;
    const unsigned short* AlB = gather ? El : Al;
    size_t ra[2], rb[2];
    int mrow[2];
    #pragma unroll
    for (int c2 = 0; c2 < 2; ++c2) {
        int mb = wave * 32 + c2 * 16;
        mrow[c2] = mb;
        int rg = m0 + mb + (lane >> 2);
        int bb = rg >> lTc, tl = rg & Tcm1;
        ra[c2] = gather ? (size_t)gather[(b_off + bb) * TT + t0 + tl] * (size_t)Kp
                        : ((size_t)bb * TT + t0 + tl) * (size_t)Kp;
        int nr = n0 + mb + (lane >> 2);
        rb[c2] = (size_t)nr * (size_t)Kp;
    }
    int klane = (lane & 3) * 8;

    f32x4 acc[4][4];
    #pragma unroll
    for (int i = 0; i < 4; ++i)
        #pragma unroll
        for (int j = 0; j < 4; ++j) acc[i][j] = (f32x4){0.f, 0.f, 0.f, 0.f};

    int fr = (lane >> 4) * 8;
    int ml = lane & 15;
    int mbase = (wave & 1) * 64;
    int nbase = (wave >> 1) * 64;

    for (int k0 = 0; k0 < Kp; k0 += 32) {
        #pragma unroll
        for (int c2 = 0; c2 < 2; ++c2) {
            GLDS(AhB + ra[c2] + k0 + klane, &Ash[mrow[c2]][0]);
            GLDS(AlB + ra[c2] + k0 + klane, &Asl[mrow[c2]][0]);
            GLDS(Wh  + rb[c2] + k0 + klane, &Bsh[mrow[c2]][0]);
            GLDS(Wl  + rb[c2] + k0 + klane, &Bsl[mrow[c2]][0]);
        }
        __syncthreads();

        bf16x8 afh[4], afl[4], bfh[4], bfl[4];
        #pragma unroll
        for (int i = 0; i < 4; ++i) {
            afh[i] = *(const bf16x8*)&Ash[mbase + i * 16 + ml][fr];
            afl[i] = *(const bf16x8*)&Asl[mbase + i * 16 + ml][fr];
            bfh[i] = *(const bf16x8*)&Bsh[nbase + i * 16 + ml][fr];
            bfl[i] = *(const bf16x8*)&Bsl[nbase + i * 16 + ml][fr];
        }
        #pragma unroll
        for (int i = 0; i < 4; ++i)
            #pragma unroll
            for (int j = 0; j < 4; ++j)
                acc[i][j] = __builtin_amdgcn_mfma_f32_16x16x32_bf16(afh[i], bfh[j], acc[i][j], 0, 0, 0);
        #pragma unroll
        for (int i = 0; i < 4; ++i)
            #pragma unroll
            for (int j = 0; j < 4; ++j)
                acc[i][j] = __builtin_amdgcn_mfma_f32_16x16x32_bf16(afh[i], bfl[j], acc[i][j], 0, 0, 0);
        #pragma unroll
        for (int i = 0; i < 4; ++i)
            #pragma unroll
            for (int j = 0; j < 4; ++j)
                acc[i][j] = __builtin_amdgcn_mfma_f32_16x16x32_bf16(afl[i], bfh[j], acc[i][j], 0, 0, 0);
        __syncthreads();
    }

    // epilogue: C/D layout col=lane&15, row=(lane>>4)*4+r; store into permuted slot
    int rq = lane >> 4;
    #pragma unroll
    for (int i = 0; i < 4; ++i) {
        int mg = m0 + mbase + i * 16 + rq * 4;
        #pragma unroll
        for (int j = 0; j < 4; ++j) {
            int ng = n0 + nbase + j * 16 + ml;
            if (ng < NG) {
                float bz = bsum[ng];
                int s = slot_of(ng);
                #pragma unroll
                for (int r = 0; r < 4; ++r)
                    G[(size_t)(mg + r) * NGP + s] = acc[i][j][r] + bz;
            }
        }
    }
}

// ---------------- recurrent scan v3: permuted slots, 1 barrier/step ----------------
// 640 threads = 10 waves. Wave w lane l owns gate column g*150+u, u=w*16+(l&15), g=l>>4.
// Whh^T (permuted) k<128 in 128 VGPRs, k=128..149 in LDS. Gate exchange via __shfl.
#define REGK  32
#define TAILP 11

__global__ __launch_bounds__(640) void scan_kernel(
    const float* __restrict__ G,       // [NBc][Tc][640] permuted x_proj+bias
    const float* __restrict__ Wt,      // [150][640] permuted Whh^T
    const int*   __restrict__ lengths,
    unsigned short* __restrict__ Aout, // [NBc][512][160] bf16-hi h, or null (layer 3)
    unsigned short* __restrict__ Alout,
    float* __restrict__ hnb,           // [256][150]
    float* __restrict__ hst, float* __restrict__ cst,   // [NBc][150] carries
    int b_off, int t0, int Tc)
{
    __shared__ __align__(16) float h_s[2][160];
    __shared__ __align__(8) float wl2[TAILP][NGP][2];

    int tid = threadIdx.x;
    int lane = tid & 63, w = tid >> 6;
    int u_loc = lane & 15, g = (lane >> 4) & 3;
    int u = w * 16 + u_loc;
    bool own = (lane < 16) && (u < HIDN);

    int l0 = blockIdx.x;
    int b  = b_off + l0;
    int len = lengths[b];
    int tmax = min(len, t0 + Tc);

    float4 wr[REGK];
    #pragma unroll
    for (int q = 0; q < REGK; ++q) {
        wr[q].x = Wt[(4 * q + 0) * NGP + tid];
        wr[q].y = Wt[(4 * q + 1) * NGP + tid];
        wr[q].z = Wt[(4 * q + 2) * NGP + tid];
        wr[q].w = Wt[(4 * q + 3) * NGP + tid];
    }
    #pragma unroll
    for (int p = 0; p < TAILP; ++p) {
        wl2[p][tid][0] = Wt[(128 + 2 * p) * NGP + tid];
        wl2[p][tid][1] = Wt[(129 + 2 * p) * NGP + tid];
    }

    float c = 0.f;
    if (tid < 160) { h_s[0][tid] = 0.f; h_s[1][tid] = 0.f; }
    if (tid < HIDN && t0 > 0) h_s[0][tid] = hst[l0 * HIDN + tid];
    if (own && t0 > 0) c = cst[l0 * HIDN + u];

    bool isg = (g == 2);                      // g-gate -> tanh
    const float* Gbase = G + (size_t)l0 * Tc * NGP + tid;
    __syncthreads();

    int p = 0;
    float gnext = (t0 < tmax) ? Gbase[(size_t)0] : 0.f;
    for (int t = t0; t < tmax; ++t) {
        float gcur = gnext;
        if (t + 1 < tmax) gnext = Gbase[(size_t)(t + 1 - t0) * NGP];   // prefetch next step
        const float* hp = &h_s[p][0];
        float acc = 0.f;
        #pragma unroll
        for (int q = 0; q < REGK; ++q) {
            float4 h4 = *(const float4*)&hp[4 * q];                    // LDS broadcast
            acc += wr[q].x * h4.x; acc += wr[q].y * h4.y;
            acc += wr[q].z * h4.z; acc += wr[q].w * h4.w;
        }
        #pragma unroll
        for (int q = 0; q < TAILP; ++q) {
            float2 wp = *(const float2*)&wl2[q][tid][0];
            float2 h2 = *(const float2*)&hp[128 + 2 * q];
            acc += wp.x * h2.x; acc += wp.y * h2.y;
        }
        float a = gcur + acc;
        // per-lane activation: sigmoid (i,f,o) or tanh (g) = 2*sigmoid(2a)-1
        float bb = isg ? 2.f * a : a;
        float e  = __expf(-bb);
        float r  = 1.f / (1.f + e);
        float av = isg ? 2.f * r - 1.f : r;
        // wave-local gate gather (columns u, u+150, u+300, u+450 live in this wave)
        float fv = __shfl(av, u_loc + 16, 64);
        float gv = __shfl(av, u_loc + 32, 64);
        float ov = __shfl(av, u_loc + 48, 64);
        if (own) {
            float cn = fv * c + av * gv;       // av = i-gate on owner lanes (g==0)
            float e2 = __expf(-2.f * cn);
            float th = 2.f / (1.f + e2) - 1.f;
            float hv = ov * th;
            c = cn;
            h_s[p ^ 1][u] = hv;
            if (Aout) {
                size_t off = ((size_t)l0 * TT + t) * KPA + u;
                unsigned short hi = f2bf(hv);
                Aout[off]  = hi;
                Alout[off] = f2bf(hv - bf2f(hi));
            }
            if (t == len - 1) hnb[b * HIDN + u] = hv;
        }
        __syncthreads();
        p ^= 1;
    }

    if (own) {
        hst[l0 * HIDN + u] = h_s[p][u];
        cst[l0 * HIDN + u] = c;
    }
}

// ---------------- fc1+relu+fc2 head ----------------
__global__ __launch_bounds__(256) void head_kernel(
    const float* __restrict__ hnb, const float* __restrict__ fc1_w,
    const float* __restrict__ fc1_b, const float* __restrict__ fc2_w,
    const float* __restrict__ fc2_b, float* __restrict__ out)
{
    __shared__ float hs[HIDN];
    __shared__ float zs[HIDN];
    int b = blockIdx.x, tid = threadIdx.x;
    if (tid < HIDN) hs[tid] = hnb[b * HIDN + tid];
    __syncthreads();
    if (tid < HIDN) {
        float acc = fc1_b[tid];
        const float* wr = fc1_w + (size_t)tid * HIDN;
        #pragma unroll 5
        for (int k = 0; k < HIDN; ++k) acc += wr[k] * hs[k];
        zs[tid] = fmaxf(acc, 0.f);
    }
    __syncthreads();
    if (tid == 0) {
        float s = fc2_b[0];
        for (int k = 0; k < HIDN; ++k) s += fc2_w[k] * zs[k];
        out[b] = s;
    }
}

extern "C" void kernel_launch(void* const* d_in, const int* in_sizes, int n_in,
                              void* d_out, int out_size, void* d_ws, size_t ws_size,
                              hipStream_t stream)
{
    const int*   x       = (const int*)d_in[0];
    const int*   lengths = (const int*)d_in[1];
    const float* emb     = (const float*)d_in[2];
    const float *Wih[4], *Whh[4], *bih[4], *bhh[4];
    for (int l = 0; l < 4; ++l) {
        Wih[l] = (const float*)d_in[3 + 4 * l];
        Whh[l] = (const float*)d_in[4 + 4 * l];
        bih[l] = (const float*)d_in[5 + 4 * l];
        bhh[l] = (const float*)d_in[6 + 4 * l];
    }
    const float* fc1_w = (const float*)d_in[19];
    const float* fc1_b = (const float*)d_in[20];
    const float* fc2_w = (const float*)d_in[21];
    const float* fc2_b = (const float*)d_in[22];

    int Kl[4]  = {300, 150, 150, 150};
    int Kp[4]  = {KPE, KPA, KPA, KPA};
    size_t wgoff[4];
    size_t wgacc = 0;
    for (int l = 0; l < 4; ++l) { wgoff[l] = wgacc; wgacc += 2 * (size_t)NGP * Kp[l]; }

    // ---- adaptive workspace sizing ----
    size_t wf = ws_size / sizeof(float);
    const size_t WFIX = 384000 + 2560 + 38400 + 512000 + 16000000;
    int NBc = 0, Tc = 0;
    for (int nb = 256; nb >= 16; nb >>= 1) {
        for (int tc = 512; tc >= 8; tc >>= 1) {
            size_t need = WFIX + (size_t)nb * 300
                        + (size_t)nb * TT * KPA                   // Ah+Al (2 bufs of bf16)
                        + (size_t)nb * tc * NGP;                  // G chunk (stride 640)
            if (need <= wf) { NBc = nb; Tc = tc; break; }
        }
        if (NBc) break;
    }
    if (!NBc) return;
    int lTc = __builtin_ctz(Tc);

    float* ws  = (float*)d_ws;
    float* Wts = ws;                                    // 4 * 96000 (permuted)
    float* bsm = Wts + 384000;                          // 4 * 640
    float* hnb = bsm + 2560;                            // 256*150
    unsigned short* Wg = (unsigned short*)(hnb + 38400);        // 1,024,000 ushorts
    unsigned short* embh = Wg + 1024000;                        // 16,000,000 ushorts
    unsigned short* embl = embh + 16000000;                     // 16,000,000 ushorts
    float* hst = (float*)(embl + 16000000);             // NBc*150
    float* cst = hst + (size_t)NBc * HIDN;              // NBc*150
    unsigned short* Ahh = (unsigned short*)(cst + (size_t)NBc * HIDN);  // NBc*512*160
    unsigned short* Ahl = Ahh + (size_t)NBc * TT * KPA;                 // NBc*512*160
    float* G   = (float*)(Ahl + (size_t)NBc * TT * KPA);                // NBc*Tc*640

    embprep_kernel<<<(50000 * KPE + 255) / 256, 256, 0, stream>>>(emb, embh, embl);
    for (int l = 0; l < 4; ++l) {
        int total = NGP * Kp[l] + HIDN * NGP + NGP;
        prep_kernel<<<(total + 255) / 256, 256, 0, stream>>>(
            Wih[l], Whh[l], bih[l], bhh[l], Kl[l], Kp[l],
            Wg + wgoff[l], Wg + wgoff[l] + (size_t)NGP * Kp[l],
            Wts + l * 96000, bsm + l * 640);
    }

    int nTc = TT / Tc;
    int nBc = NBATCH / NBc;
    dim3 ggrid((unsigned)(NBc * Tc / 128), 5);
    for (int bc = 0; bc < nBc; ++bc) {
        int b_off = bc * NBc;
        for (int l = 0; l < 4; ++l) {
            const unsigned short* Wh = Wg + wgoff[l];
            const unsigned short* Wl = Wh + (size_t)NGP * Kp[l];
            for (int tc = 0; tc < nTc; ++tc) {
                int t0 = tc * Tc;
                gemm_kernel<<<ggrid, 256, 0, stream>>>(
                    (l == 0) ? nullptr : Ahh, (l == 0) ? nullptr : Ahl,
                    (l == 0) ? x : nullptr, embh, embl,
                    Kp[l], Wh, Wl, bsm + l * 640, lengths, G, b_off, t0, lTc);
                scan_kernel<<<NBc, 640, 0, stream>>>(
                    G, Wts + l * 96000, lengths,
                    (l == 3) ? nullptr : Ahh, (l == 3) ? nullptr : Ahl,
                    hnb, hst, cst, b_off, t0, Tc);
            }
        }
    }
    head_kernel<<<256, 256, 0, stream>>>(hnb, fc1_w, fc1_b, fc2_w, fc2_b, (float*)d_out);
}